// Round 11
// baseline (169.685 us; speedup 1.0000x reference)
//
#include <hip/hip_runtime.h>
#include <math.h>

#define N_RAYS 65536
#define LAMBDA_OPACITY 0.001f
#define LAMBDA_DISTORTION 0.001f

// native clang vector type — accepted by __builtin_nontemporal_load
typedef float f32x4 __attribute__((ext_vector_type(4)));

// ---------------------------------------------------------------------------
// DPP wave64 inclusive-add scan (canonical gfx9 sequence, all-VALU) —
// verified R5/R7/R10.
// ---------------------------------------------------------------------------
template <int CTRL, int ROW_MASK>
__device__ __forceinline__ float dpp_add(float x) {
    int s = __builtin_amdgcn_update_dpp(0, __float_as_int(x),
                                        CTRL, ROW_MASK, 0xf, false);
    return x + __int_as_float(s);
}

__device__ __forceinline__ float wave64_incl_scan(float x) {
    x = dpp_add<0x111, 0xf>(x);  // row_shr:1
    x = dpp_add<0x112, 0xf>(x);  // row_shr:2
    x = dpp_add<0x114, 0xf>(x);  // row_shr:4
    x = dpp_add<0x118, 0xf>(x);  // row_shr:8
    x = dpp_add<0x142, 0xa>(x);  // row_bcast:15 -> rows 1,3
    x = dpp_add<0x143, 0xc>(x);  // row_bcast:31 -> rows 2,3
    return x;
}

// one ray's verified datapath (R5/R7/R10), given its 3 quads + meta
__device__ __forceinline__ void process_ray(
    int lane, int ray, int out_ray, int start, int count,
    f32x4 vw, f32x4 vt, f32x4 vd,
    const float* __restrict__ ws, const float* __restrict__ ts,
    const float* __restrict__ deltas, float* __restrict__ out)
{
    float w[4] = {0.f, 0.f, 0.f, 0.f};
    float t[4] = {0.f, 0.f, 0.f, 0.f};
    float d[4] = {0.f, 0.f, 0.f, 0.f};

    if (start == 192 * ray && count == 192) {
        if (lane < 48) {
            w[0]=vw.x; w[1]=vw.y; w[2]=vw.z; w[3]=vw.w;
            t[0]=vt.x; t[1]=vt.y; t[2]=vt.z; t[3]=vt.w;
            d[0]=vd.x; d[1]=vd.y; d[2]=vd.z; d[3]=vd.w;
        }
    } else {
        // generic fallback: any start/count, guarded scalar loads
        #pragma unroll
        for (int e = 0; e < 4; ++e) {
            const int p  = 4 * lane + e;
            const bool ok = p < count;
            w[e] = ok ? ws[start + p]     : 0.f;
            t[e] = ok ? ts[start + p]     : 0.f;
            d[e] = ok ? deltas[start + p] : 0.f;
        }
    }

    const float wt0 = w[0] * t[0], wt1 = w[1] * t[1];
    const float wt2 = w[2] * t[2], wt3 = w[3] * t[3];
    const float lw  = (w[0] + w[1]) + (w[2] + w[3]);
    const float lwt = (wt0 + wt1) + (wt2 + wt3);

    const float iw  = wave64_incl_scan(lw);
    const float iwt = wave64_incl_scan(lwt);

    float e_w  = iw  - lw;
    float e_wt = iwt - lwt;

    float acc = 0.f;
    #pragma unroll
    for (int e = 0; e < 4; ++e) {
        acc += 2.f * w[e] * (t[e] * e_w - e_wt) + w[e] * w[e] * d[e] * (1.f / 3.f);
        e_w  += w[e];
        e_wt += w[e] * t[e];
    }

    const float tot = wave64_incl_scan(acc);
    if (lane == 63)
        out[3 * N_RAYS + out_ray] = LAMBDA_DISTORTION * tot;
}

// ---------------------------------------------------------------------------
// Distortion: R10 winner + 2 rays per wave. All 6 nt data loads + both meta
// loads issue before the sched_barrier -> double the bytes-in-flight per
// wave while keeping 32768 waves of TLP.
// ---------------------------------------------------------------------------
__global__ __launch_bounds__(256)
void distortion_kernel(
    const float* __restrict__ ws,
    const float* __restrict__ deltas,
    const float* __restrict__ ts,
    const int*   __restrict__ rays_a,
    float* __restrict__ out)
{
    const int lane = threadIdx.x & 63;
    const int wid  = blockIdx.x * 4 + (threadIdx.x >> 6);
    const int rayA = 2 * wid;
    const int rayB = 2 * wid + 1;

    // --- speculative nontemporal data loads for BOTH rays ---
    f32x4 vwA = {0,0,0,0}, vtA = {0,0,0,0}, vdA = {0,0,0,0};
    f32x4 vwB = {0,0,0,0}, vtB = {0,0,0,0}, vdB = {0,0,0,0};
    if (lane < 48) {
        const int spA = 192 * rayA + 4 * lane;
        const int spB = 192 * rayB + 4 * lane;
        vwA = __builtin_nontemporal_load((const f32x4*)(ws     + spA));
        vtA = __builtin_nontemporal_load((const f32x4*)(ts     + spA));
        vdA = __builtin_nontemporal_load((const f32x4*)(deltas + spA));
        vwB = __builtin_nontemporal_load((const f32x4*)(ws     + spB));
        vtB = __builtin_nontemporal_load((const f32x4*)(ts     + spB));
        vdB = __builtin_nontemporal_load((const f32x4*)(deltas + spB));
    }

    // --- meta loads, same round trip as the data loads ---
    const int orA = rays_a[rayA * 3 + 0];
    const int stA = rays_a[rayA * 3 + 1];
    const int ctA = rays_a[rayA * 3 + 2];
    const int orB = rays_a[rayB * 3 + 0];
    const int stB = rays_a[rayB * 3 + 1];
    const int ctB = rays_a[rayB * 3 + 2];

    __builtin_amdgcn_sched_barrier(0);

    process_ray(lane, rayA, orA, stA, ctA, vwA, vtA, vdA, ws, ts, deltas, out);
    process_ray(lane, rayB, orB, stB, ctB, vwB, vtB, vdB, ws, ts, deltas, out);
}

// ---------------------------------------------------------------------------
// Per-ray cheap terms: 1 thread per ray, fully coalesced (~6 MB total).
// ---------------------------------------------------------------------------
__global__ __launch_bounds__(256)
void perray_kernel(
    const float* __restrict__ rgb_coarse,
    const float* __restrict__ rgb_fine,
    const float* __restrict__ rgb_target,
    const float* __restrict__ depth,
    const float* __restrict__ depth_target,
    const float* __restrict__ opacity,
    float* __restrict__ out)
{
    const int r = blockIdx.x * blockDim.x + threadIdx.x;
    if (r >= N_RAYS) return;

    const float rt0 = rgb_target[r * 3 + 0];
    const float rt1 = rgb_target[r * 3 + 1];
    const float rt2 = rgb_target[r * 3 + 2];
    const float c0 = rgb_coarse[r * 3 + 0] - rt0;
    const float c1 = rgb_coarse[r * 3 + 1] - rt1;
    const float c2 = rgb_coarse[r * 3 + 2] - rt2;
    const float f0 = rgb_fine[r * 3 + 0] - rt0;
    const float f1 = rgb_fine[r * 3 + 1] - rt1;
    const float f2 = rgb_fine[r * 3 + 2] - rt2;

    out[r] = (c0 * c0 + c1 * c1 + c2 * c2) * (1.f / 3.f)
           + (f0 * f0 + f1 * f1 + f2 * f2) * (1.f / 3.f);

    out[N_RAYS + r] = fabsf(depth[r] - depth_target[r]);

    const float o = opacity[r] + 1e-10f;
    out[2 * N_RAYS + r] = LAMBDA_OPACITY * (-o * logf(o));
}

extern "C" void kernel_launch(void* const* d_in, const int* in_sizes, int n_in,
                              void* d_out, int out_size, void* d_ws, size_t ws_size,
                              hipStream_t stream) {
    const float* rgb_coarse   = (const float*)d_in[0];
    const float* rgb_fine     = (const float*)d_in[1];
    const float* rgb_target   = (const float*)d_in[2];
    const float* depth        = (const float*)d_in[3];
    const float* depth_target = (const float*)d_in[4];
    const float* opacity      = (const float*)d_in[5];
    const float* ws           = (const float*)d_in[6];
    const float* deltas       = (const float*)d_in[7];
    const float* ts           = (const float*)d_in[8];
    const int*   rays_a       = (const int*)d_in[9];
    float* out = (float*)d_out;

    // 4 waves per block, 2 rays per wave
    distortion_kernel<<<N_RAYS / 8, 256, 0, stream>>>(
        ws, deltas, ts, rays_a, out);

    perray_kernel<<<N_RAYS / 256, 256, 0, stream>>>(
        rgb_coarse, rgb_fine, rgb_target, depth, depth_target, opacity, out);
}

// Round 12
// 165.989 us; speedup vs baseline: 1.0223x; 1.0223x over previous
//
#include <hip/hip_runtime.h>
#include <math.h>

#define N_RAYS 65536
#define LAMBDA_OPACITY 0.001f
#define LAMBDA_DISTORTION 0.001f

// native clang vector type — accepted by __builtin_nontemporal_load
typedef float f32x4 __attribute__((ext_vector_type(4)));

#define NB_PERRAY (N_RAYS / 256)   // 256 perray blocks, dispatched first
#define NB_DIST   (N_RAYS / 4)     // 16384 distortion blocks (4 waves, 1 ray/wave)

// ---------------------------------------------------------------------------
// DPP wave64 inclusive-add scan (canonical gfx9 sequence, all-VALU) —
// verified R5/R7/R10.
// ---------------------------------------------------------------------------
template <int CTRL, int ROW_MASK>
__device__ __forceinline__ float dpp_add(float x) {
    int s = __builtin_amdgcn_update_dpp(0, __float_as_int(x),
                                        CTRL, ROW_MASK, 0xf, false);
    return x + __int_as_float(s);
}

__device__ __forceinline__ float wave64_incl_scan(float x) {
    x = dpp_add<0x111, 0xf>(x);  // row_shr:1
    x = dpp_add<0x112, 0xf>(x);  // row_shr:2
    x = dpp_add<0x114, 0xf>(x);  // row_shr:4
    x = dpp_add<0x118, 0xf>(x);  // row_shr:8
    x = dpp_add<0x142, 0xa>(x);  // row_bcast:15 -> rows 1,3
    x = dpp_add<0x143, 0xc>(x);  // row_bcast:31 -> rows 2,3
    return x;
}

// ---------------------------------------------------------------------------
// Fused kernel. Blocks [0, NB_PERRAY) do the cheap per-ray terms (dispatched
// first -> fully hidden under distortion). Blocks [NB_PERRAY, +NB_DIST) run
// the R10-winning distortion path: one wave per ray, speculative nt loads
// concurrent with the meta load, DPP scans, lane-63 store.
// ---------------------------------------------------------------------------
__global__ __launch_bounds__(256)
void fused_kernel(
    const float* __restrict__ rgb_coarse,
    const float* __restrict__ rgb_fine,
    const float* __restrict__ rgb_target,
    const float* __restrict__ depth,
    const float* __restrict__ depth_target,
    const float* __restrict__ opacity,
    const float* __restrict__ ws,
    const float* __restrict__ deltas,
    const float* __restrict__ ts,
    const int*   __restrict__ rays_a,
    float* __restrict__ out)
{
    if (blockIdx.x < NB_PERRAY) {
        // ---------------- per-ray cheap terms ----------------
        const int r = blockIdx.x * 256 + threadIdx.x;

        const float rt0 = __builtin_nontemporal_load(rgb_target + r * 3 + 0);
        const float rt1 = __builtin_nontemporal_load(rgb_target + r * 3 + 1);
        const float rt2 = __builtin_nontemporal_load(rgb_target + r * 3 + 2);
        const float c0 = __builtin_nontemporal_load(rgb_coarse + r * 3 + 0) - rt0;
        const float c1 = __builtin_nontemporal_load(rgb_coarse + r * 3 + 1) - rt1;
        const float c2 = __builtin_nontemporal_load(rgb_coarse + r * 3 + 2) - rt2;
        const float f0 = __builtin_nontemporal_load(rgb_fine + r * 3 + 0) - rt0;
        const float f1 = __builtin_nontemporal_load(rgb_fine + r * 3 + 1) - rt1;
        const float f2 = __builtin_nontemporal_load(rgb_fine + r * 3 + 2) - rt2;

        out[r] = (c0 * c0 + c1 * c1 + c2 * c2) * (1.f / 3.f)
               + (f0 * f0 + f1 * f1 + f2 * f2) * (1.f / 3.f);

        out[N_RAYS + r] = fabsf(__builtin_nontemporal_load(depth + r)
                              - __builtin_nontemporal_load(depth_target + r));

        const float o = __builtin_nontemporal_load(opacity + r) + 1e-10f;
        out[2 * N_RAYS + r] = LAMBDA_OPACITY * (-o * logf(o));
        return;
    }

    // ---------------- distortion (R10 winner) ----------------
    const int lane = threadIdx.x & 63;
    const int ray  = (blockIdx.x - NB_PERRAY) * 4 + (threadIdx.x >> 6);

    // speculative nontemporal data loads (identity layout)
    f32x4 vw = {0.f, 0.f, 0.f, 0.f};
    f32x4 vt = {0.f, 0.f, 0.f, 0.f};
    f32x4 vd = {0.f, 0.f, 0.f, 0.f};
    if (lane < 48) {
        const int sp = 192 * ray + 4 * lane;
        vw = __builtin_nontemporal_load((const f32x4*)(ws     + sp));
        vt = __builtin_nontemporal_load((const f32x4*)(ts     + sp));
        vd = __builtin_nontemporal_load((const f32x4*)(deltas + sp));
    }

    // meta load, independent of the data loads -> same round trip
    const int out_ray = rays_a[ray * 3 + 0];
    const int start   = rays_a[ray * 3 + 1];
    const int count   = rays_a[ray * 3 + 2];

    __builtin_amdgcn_sched_barrier(0);

    float w[4] = {0.f, 0.f, 0.f, 0.f};
    float t[4] = {0.f, 0.f, 0.f, 0.f};
    float d[4] = {0.f, 0.f, 0.f, 0.f};

    if (start == 192 * ray && count == 192) {
        if (lane < 48) {
            w[0]=vw.x; w[1]=vw.y; w[2]=vw.z; w[3]=vw.w;
            t[0]=vt.x; t[1]=vt.y; t[2]=vt.z; t[3]=vt.w;
            d[0]=vd.x; d[1]=vd.y; d[2]=vd.z; d[3]=vd.w;
        }
    } else {
        // generic fallback: any start/count, guarded scalar loads
        #pragma unroll
        for (int e = 0; e < 4; ++e) {
            const int p  = 4 * lane + e;
            const bool ok = p < count;
            w[e] = ok ? ws[start + p]     : 0.f;
            t[e] = ok ? ts[start + p]     : 0.f;
            d[e] = ok ? deltas[start + p] : 0.f;
        }
    }

    // per-lane quad totals
    const float wt0 = w[0] * t[0], wt1 = w[1] * t[1];
    const float wt2 = w[2] * t[2], wt3 = w[3] * t[3];
    const float lw  = (w[0] + w[1]) + (w[2] + w[3]);
    const float lwt = (wt0 + wt1) + (wt2 + wt3);

    // DPP inclusive scans over quad totals (two independent chains)
    const float iw  = wave64_incl_scan(lw);
    const float iwt = wave64_incl_scan(lwt);

    // exclusive base for this quad
    float e_w  = iw  - lw;
    float e_wt = iwt - lwt;

    // lane-local sequential exclusive accumulation over the 4 samples
    float acc = 0.f;
    #pragma unroll
    for (int e = 0; e < 4; ++e) {
        acc += 2.f * w[e] * (t[e] * e_w - e_wt) + w[e] * w[e] * d[e] * (1.f / 3.f);
        e_w  += w[e];
        e_wt += w[e] * t[e];
    }

    // ray total via one more DPP scan; lane 63 holds the full sum
    const float tot = wave64_incl_scan(acc);
    if (lane == 63)
        out[3 * N_RAYS + out_ray] = LAMBDA_DISTORTION * tot;
}

extern "C" void kernel_launch(void* const* d_in, const int* in_sizes, int n_in,
                              void* d_out, int out_size, void* d_ws, size_t ws_size,
                              hipStream_t stream) {
    const float* rgb_coarse   = (const float*)d_in[0];
    const float* rgb_fine     = (const float*)d_in[1];
    const float* rgb_target   = (const float*)d_in[2];
    const float* depth        = (const float*)d_in[3];
    const float* depth_target = (const float*)d_in[4];
    const float* opacity      = (const float*)d_in[5];
    const float* ws           = (const float*)d_in[6];
    const float* deltas       = (const float*)d_in[7];
    const float* ts           = (const float*)d_in[8];
    const int*   rays_a       = (const int*)d_in[9];
    float* out = (float*)d_out;

    fused_kernel<<<NB_PERRAY + NB_DIST, 256, 0, stream>>>(
        rgb_coarse, rgb_fine, rgb_target, depth, depth_target, opacity,
        ws, deltas, ts, rays_a, out);
}